// Round 4
// baseline (517.612 us; speedup 1.0000x reference)
//
#include <hip/hip_runtime.h>
#include <hip/hip_bf16.h>

// QuantizedSimpleSSM — round 9: LDS-pipe relief. Evidence: R7 and R8 both run
// at ~15.5 cyc per ds_read_b128 per CU (32768 reads in ~505-530k cyc)
// regardless of 2 vs 4 blocks/CU -> per-CU LDS return BW (~85 B/cyc, m134) is
// the wall, not latency/barriers/occupancy (FMA util 52%, VALUBusy 65%).
// Fix: a-frags are CONTIGUOUS in global (u is [b][d][t], S is [b][n][t]) ->
// read them straight from global (L1/L2-resident, HBM at 11%), keep only W in
// LDS. LDS reads per wave-kstep 4 -> 2 (below VALU demand), staging writes
// halve, LDS 32KB -> 16KB. Same FMA values in same order -> bitwise identical.
// Numerics contract (absmax 0.0 since R2): every output element is one fp32
// FMA chain in strictly ascending k; recurrence mul-then-add + q8.

#define DINX 512
#define LSEQ 512
#define NDIM 512

__device__ __forceinline__ float q8(float x) {
    float xa = fabsf(x);
    float w  = __fadd_rn(xa, 1e-8f);
    int e = (int)((__float_as_uint(w) >> 23) & 0xFFu) - 127;   // floor(log2(w))
    e = e < -7 ? -7 : (e > 7 ? 7 : e);
    float p    = __int_as_float((unsigned)((e + 127) << 23));   // exact 2^e
    float invp = __int_as_float((unsigned)((127 - e) << 23));   // exact 2^-e
    float t  = __fmul_rn(__fsub_rn(__fmul_rn(xa, invp), 1.0f), 8.0f);
    float m  = __fmul_rn(rintf(t), 0.125f);                     // half-to-even
    float r  = __fmul_rn(__fadd_rn(1.0f, m), p);
    return copysignf(r, x);
}

// out[c][r] = q8(in[r][c]) for three 512x512 matrices; block (0,0,0) also
// quants the A vector. grid (16,16,3), block 256.
__global__ __launch_bounds__(256) void quantT3A(const float* __restrict__ B,
                                                const float* __restrict__ C,
                                                const float* __restrict__ D,
                                                const float* __restrict__ A,
                                                float* __restrict__ Bqt,
                                                float* __restrict__ Cqt,
                                                float* __restrict__ Dqt,
                                                float* __restrict__ Aq) {
    __shared__ float tl[32][33];
    if (blockIdx.z == 0 && blockIdx.x == 0 && blockIdx.y == 0) {
        Aq[threadIdx.x]       = q8(A[threadIdx.x]);
        Aq[256 + threadIdx.x] = q8(A[256 + threadIdx.x]);
    }
    const float* in = blockIdx.z == 0 ? B : (blockIdx.z == 1 ? C : D);
    float* out      = blockIdx.z == 0 ? Bqt : (blockIdx.z == 1 ? Cqt : Dqt);
    const int r0 = blockIdx.y * 32, c0 = blockIdx.x * 32;
    const int x = threadIdx.x & 31, y = threadIdx.x >> 5;   // 32 x 8
#pragma unroll
    for (int i = 0; i < 32; i += 8)
        tl[y + i][x] = q8(in[(r0 + y + i) * 512 + c0 + x]);
    __syncthreads();
#pragma unroll
    for (int i = 0; i < 32; i += 8)
        out[(c0 + y + i) * 512 + r0 + x] = tl[x][y + i];
}

// acc[p][i][q][j] += sum_k X[k][m0 + p*64 + tx*4 + i] * W[k][n0 + q*64 + ty*4 + j],
// k strictly ascending. X, W are [KTOT][512] row-major; X's inner dim is
// CONTIGUOUS per a-frag, so a-frags load straight from global (one 256-B
// segment per wave-load, L1/L2-resident). Only W is LDS-staged ([32][128],
// 16 KB, BK=32 per barrier pair; b-reads broadcast within quarter-waves).
__device__ __forceinline__ void gemm_pass(const float* __restrict__ X,
                                          const float* __restrict__ W,
                                          int m0, int n0, int KTOT,
                                          float (&acc)[2][4][2][4],
                                          float (*Ws)[128], int tid) {
    const int tx = tid & 15, ty = tid >> 4;
    const int srow = tid >> 4, sseg4 = (tid & 15) * 4;   // 16 rows x 16 chunks
    const float* wp = W + (size_t)srow * 512 + n0 + sseg4;
    const float* xp = X + m0 + tx * 4;                   // per-lane a base, k=0
    for (int k0 = 0; k0 < KTOT; k0 += 32) {
        // stage W rows srow and srow+16 of the 32-row tile, both halves (0/64)
        float4 w0 = *(const float4*)wp;
        float4 w1 = *(const float4*)(wp + 64);
        float4 w2 = *(const float4*)(wp + 16 * 512);
        float4 w3 = *(const float4*)(wp + 16 * 512 + 64);
        wp += 32 * 512;
        __syncthreads();                 // prev-tile reads done before overwrite
        *(float4*)&Ws[srow][sseg4]           = w0;
        *(float4*)&Ws[srow][64 + sseg4]      = w1;
        *(float4*)&Ws[16 + srow][sseg4]      = w2;
        *(float4*)&Ws[16 + srow][64 + sseg4] = w3;
        __syncthreads();
#pragma unroll
        for (int k = 0; k < 32; ++k) {
            float a[2][4], b[2][4];
            *(float4*)&a[0][0] = *(const float4*)(xp);
            *(float4*)&a[1][0] = *(const float4*)(xp + 64);
            xp += 512;
            *(float4*)&b[0][0] = *(const float4*)&Ws[k][ty * 4];
            *(float4*)&b[1][0] = *(const float4*)&Ws[k][64 + ty * 4];
#pragma unroll
            for (int p = 0; p < 2; ++p)
#pragma unroll
                for (int i = 0; i < 4; ++i)
#pragma unroll
                    for (int q = 0; q < 2; ++q)
#pragma unroll
                        for (int j = 0; j < 4; ++j)
                            acc[p][i][q][j] = fmaf(a[p][i], b[q][j], acc[p][i][q][j]);
        }
    }
}

// Fused R + Y_D kernel. grid (4,4,64), block 256, 4 blocks/CU co-resident.
// z<32:  R[b][t][n] = sum_d u[b][d][t] * Bqt[d][n]           (raw)
// z>=32: Pd[b][o][t] = sum_d u[b][d][t] * Dqt[d][o]          (raw, into Y buf)
__global__ __launch_bounds__(256, 4) void gemm_RD(const float* __restrict__ u,
                                                  const float* __restrict__ Bqt,
                                                  const float* __restrict__ Dqt,
                                                  float* __restrict__ R,
                                                  float* __restrict__ Pd) {
    __shared__ float Ws[32][128];
    const int zz = blockIdx.z;
    const int b  = zz & 31;
    const bool isR = zz < 32;
    const int t0 = blockIdx.x * 128, n0 = blockIdx.y * 128;
    const int tid = threadIdx.x;
    const int tx = tid & 15, ty = tid >> 4;
    const float* ub = u + (size_t)b * (DINX * LSEQ);
    const float* Wm = isR ? Bqt : Dqt;
    float acc[2][4][2][4] = {};
    gemm_pass(ub, Wm, t0, n0, DINX, acc, Ws, tid);
    if (isR) {
        float* Rb = R + (size_t)b * (LSEQ * NDIM);
#pragma unroll
        for (int p = 0; p < 2; ++p)
#pragma unroll
            for (int i = 0; i < 4; ++i) {
                float* row = Rb + (size_t)(t0 + p * 64 + tx * 4 + i) * NDIM + n0;
                *(float4*)(row + ty * 4)      = make_float4(acc[p][i][0][0], acc[p][i][0][1],
                                                            acc[p][i][0][2], acc[p][i][0][3]);
                *(float4*)(row + 64 + ty * 4) = make_float4(acc[p][i][1][0], acc[p][i][1][1],
                                                            acc[p][i][1][2], acc[p][i][1][3]);
            }
    } else {
        float* Yb = Pd + (size_t)b * (NDIM * LSEQ);
#pragma unroll
        for (int q = 0; q < 2; ++q)
#pragma unroll
            for (int j = 0; j < 4; ++j) {
                float* row = Yb + (size_t)(n0 + q * 64 + ty * 4 + j) * LSEQ + t0;
                *(float4*)(row + tx * 4)      = make_float4(acc[0][0][q][j], acc[0][1][q][j],
                                                            acc[0][2][q][j], acc[0][3][q][j]);
                *(float4*)(row + 64 + tx * 4) = make_float4(acc[1][0][q][j], acc[1][1][q][j],
                                                            acc[1][2][q][j], acc[1][3][q][j]);
            }
    }
}

// Per-(b, n-chunk) recurrence (bitwise np: mul-then-add, q8). Writes S[b][n][t].
// grid (32, 8), block 64 -> 256 blocks, one chain-wave per CU.
__global__ __launch_bounds__(64) void recur(const float* __restrict__ R,
                                            const float* __restrict__ Aq,
                                            float* __restrict__ S) {
    __shared__ float tile[16][68];
    const int b  = blockIdx.x;
    const int n0 = blockIdx.y * 64;
    const int n  = threadIdx.x;                 // 0..63
    const float a = Aq[n0 + n];
    const float* Rb = R + (size_t)b * (LSEQ * NDIM) + n0;
    float* Sb = S + (size_t)b * (NDIM * LSEQ) + (size_t)n0 * LSEQ;
    float s = 0.0f;
    const int c = (n & 3) * 4;
    const int rbase = n >> 2;                   // 0..15
    for (int t0 = 0; t0 < LSEQ; t0 += 16) {
#pragma unroll
        for (int tt = 0; tt < 16; ++tt) {
            float r = Rb[(size_t)(t0 + tt) * NDIM + n];
            s = q8(__fadd_rn(__fmul_rn(s, a), r));
            tile[tt][n] = s;
        }
        __syncthreads();
#pragma unroll
        for (int p = 0; p < 4; ++p) {
            int row = p * 16 + rbase;
            float4 v = make_float4(tile[c + 0][row], tile[c + 1][row],
                                   tile[c + 2][row], tile[c + 3][row]);
            *(float4*)(Sb + (size_t)row * LSEQ + t0 + c) = v;
        }
        __syncthreads();
    }
}

// Y[b][o][t] = q8( (sum_n S[n][t]*Cqt[n][o]) + Pd[b][o][t] ), Pd staged in Y.
// grid (4,4,32), block 256.
__global__ __launch_bounds__(256) void gemm_YC(const float* __restrict__ S,
                                               const float* __restrict__ Cqt,
                                               float* __restrict__ Y) {
    __shared__ float Ws[32][128];
    const int b  = blockIdx.z;
    const int t0 = blockIdx.x * 128, o0 = blockIdx.y * 128;
    const int tid = threadIdx.x;
    const int tx = tid & 15, ty = tid >> 4;
    const float* Sb = S + (size_t)b * (NDIM * LSEQ);
    float acc[2][4][2][4] = {};
    gemm_pass(Sb, Cqt, t0, o0, NDIM, acc, Ws, tid);

    float* Yb = Y + (size_t)b * (NDIM * LSEQ);
#pragma unroll
    for (int q = 0; q < 2; ++q)
#pragma unroll
        for (int j = 0; j < 4; ++j) {
            float* row = Yb + (size_t)(o0 + q * 64 + ty * 4 + j) * LSEQ + t0;
            float4 v0 = *(const float4*)(row + tx * 4);
            float4 v1 = *(const float4*)(row + 64 + tx * 4);
            *(float4*)(row + tx * 4) =
                make_float4(q8(__fadd_rn(acc[0][0][q][j], v0.x)),
                            q8(__fadd_rn(acc[0][1][q][j], v0.y)),
                            q8(__fadd_rn(acc[0][2][q][j], v0.z)),
                            q8(__fadd_rn(acc[0][3][q][j], v0.w)));
            *(float4*)(row + 64 + tx * 4) =
                make_float4(q8(__fadd_rn(acc[1][0][q][j], v1.x)),
                            q8(__fadd_rn(acc[1][1][q][j], v1.y)),
                            q8(__fadd_rn(acc[1][2][q][j], v1.z)),
                            q8(__fadd_rn(acc[1][3][q][j], v1.w)));
        }
}

extern "C" void kernel_launch(void* const* d_in, const int* in_sizes, int n_in,
                              void* d_out, int out_size, void* d_ws, size_t ws_size,
                              hipStream_t stream) {
    const float* u = (const float*)d_in[0];   // (32, 512, 512)
    const float* A = (const float*)d_in[1];   // (512,)
    const float* B = (const float*)d_in[2];   // (512, 512)
    const float* C = (const float*)d_in[3];   // (512, 512)
    const float* D = (const float*)d_in[4];   // (512, 512)

    float* ws  = (float*)d_ws;
    float* Aq  = ws;                    // 512
    float* Bqt = Aq + 512;              // 262144  [d][n]
    float* Cqt = Bqt + 262144;          // 262144  [n][o]
    float* Dqt = Cqt + 262144;          // 262144  [d][o]
    float* R   = Dqt + 262144;          // 8388608 [b][t][n]
    float* S   = R + 8388608;           // 8388608 [b][n][t]
    float* Y   = (float*)d_out;         // 8388608 [b][o][t] (also Pd scratch)

    quantT3A<<<dim3(16, 16, 3), 256, 0, stream>>>(B, C, D, A, Bqt, Cqt, Dqt, Aq);
    gemm_RD<<<dim3(4, 4, 64), 256, 0, stream>>>(u, Bqt, Dqt, R, Y);
    recur<<<dim3(32, 8), 64, 0, stream>>>(R, Aq, S);
    gemm_YC<<<dim3(4, 4, 32), 256, 0, stream>>>(S, Cqt, Y);
}

// Round 5
// 498.622 us; speedup vs baseline: 1.0381x; 1.0381x over previous
//
#include <hip/hip_runtime.h>
#include <hip/hip_bf16.h>

// QuantizedSimpleSSM — round 10: cut LDS bytes/FMA. Invariant from R7/R8/R9:
// elapsed == ~15.5 cyc per ds_read_b128 per CU at any occupancy -> LDS return
// path is the wall (FMA util 52%). Bytes/FMA is set by the register tile:
// 8x8 = 16 operand floats / 64 FMA. This round: 8(m)x16(n) per thread = 24
// floats / 128 FMA (-25% LDS traffic), 256-thr block covers 128x256, acc=128
// VGPR, launch_bounds(256,2) -> 8 waves/CU as before, LDS 48KB x 2 blocks/CU.
// R9's global-direct a-frags reverted (VGPR fell to 64, latency exposed).
// Chain order per output unchanged (ascending k, one fmaf chain) -> bitwise.
// Numerics contract (absmax 0.0 since R2): every output element is one fp32
// FMA chain in strictly ascending k; recurrence mul-then-add + q8.

#define DINX 512
#define LSEQ 512
#define NDIM 512

__device__ __forceinline__ float q8(float x) {
    float xa = fabsf(x);
    float w  = __fadd_rn(xa, 1e-8f);
    int e = (int)((__float_as_uint(w) >> 23) & 0xFFu) - 127;   // floor(log2(w))
    e = e < -7 ? -7 : (e > 7 ? 7 : e);
    float p    = __int_as_float((unsigned)((e + 127) << 23));   // exact 2^e
    float invp = __int_as_float((unsigned)((127 - e) << 23));   // exact 2^-e
    float t  = __fmul_rn(__fsub_rn(__fmul_rn(xa, invp), 1.0f), 8.0f);
    float m  = __fmul_rn(rintf(t), 0.125f);                     // half-to-even
    float r  = __fmul_rn(__fadd_rn(1.0f, m), p);
    return copysignf(r, x);
}

// out[c][r] = q8(in[r][c]) for three 512x512 matrices; block (0,0,0) also
// quants the A vector. grid (16,16,3), block 256.
__global__ __launch_bounds__(256) void quantT3A(const float* __restrict__ B,
                                                const float* __restrict__ C,
                                                const float* __restrict__ D,
                                                const float* __restrict__ A,
                                                float* __restrict__ Bqt,
                                                float* __restrict__ Cqt,
                                                float* __restrict__ Dqt,
                                                float* __restrict__ Aq) {
    __shared__ float tl[32][33];
    if (blockIdx.z == 0 && blockIdx.x == 0 && blockIdx.y == 0) {
        Aq[threadIdx.x]       = q8(A[threadIdx.x]);
        Aq[256 + threadIdx.x] = q8(A[256 + threadIdx.x]);
    }
    const float* in = blockIdx.z == 0 ? B : (blockIdx.z == 1 ? C : D);
    float* out      = blockIdx.z == 0 ? Bqt : (blockIdx.z == 1 ? Cqt : Dqt);
    const int r0 = blockIdx.y * 32, c0 = blockIdx.x * 32;
    const int x = threadIdx.x & 31, y = threadIdx.x >> 5;   // 32 x 8
#pragma unroll
    for (int i = 0; i < 32; i += 8)
        tl[y + i][x] = q8(in[(r0 + y + i) * 512 + c0 + x]);
    __syncthreads();
#pragma unroll
    for (int i = 0; i < 32; i += 8)
        out[(c0 + y + i) * 512 + r0 + x] = tl[x][y + i];
}

// acc[p][i][q][j] += sum_k X[k][m0 + p*64 + tx*4 + i] * W[k][n0 + q*64 + ty*4 + j]
// with q in 0..3 (256-wide n-tile), k strictly ascending. X,W are [KTOT][512]
// row-major. LDS: Xs[32][128] (16KB) + Ws[32][256] (32KB), single-buffered,
// BK=32 per barrier pair. a-reads: 16 distinct float4/wave (2-way bank alias,
// free, 4x broadcast); b-reads: 4 distinct float4/wave (16x broadcast).
__device__ __forceinline__ void gemm_pass16(const float* __restrict__ X,
                                            const float* __restrict__ W,
                                            int m0, int n0, int KTOT,
                                            float (&acc)[2][4][4][4],
                                            float (*Xs)[128], float (*Ws)[256],
                                            int tid) {
    const int tx = tid & 15, ty = tid >> 4;              // 16 x 16 thread grid
    const int srow = tid >> 4, sseg4 = (tid & 15) * 4;   // X staging: 16r x 16c
    const int wrow = tid >> 5, wseg4 = (tid & 31) * 4;   // W staging: 8r x 32c
    const float* xp = X + (size_t)srow * 512 + m0 + sseg4;
    const float* wp = W + (size_t)wrow * 512 + n0 + wseg4;
    for (int k0 = 0; k0 < KTOT; k0 += 32) {
        float4 x0 = *(const float4*)xp;
        float4 x1 = *(const float4*)(xp + 64);
        float4 x2 = *(const float4*)(xp + 16 * 512);
        float4 x3 = *(const float4*)(xp + 16 * 512 + 64);
        float4 w0 = *(const float4*)wp;
        float4 w1 = *(const float4*)(wp + 128);
        float4 w2 = *(const float4*)(wp + 8 * 512);
        float4 w3 = *(const float4*)(wp + 8 * 512 + 128);
        float4 w4 = *(const float4*)(wp + 16 * 512);
        float4 w5 = *(const float4*)(wp + 16 * 512 + 128);
        float4 w6 = *(const float4*)(wp + 24 * 512);
        float4 w7 = *(const float4*)(wp + 24 * 512 + 128);
        xp += 32 * 512; wp += 32 * 512;
        __syncthreads();                 // prev-tile reads done before overwrite
        *(float4*)&Xs[srow][sseg4]            = x0;
        *(float4*)&Xs[srow][64 + sseg4]       = x1;
        *(float4*)&Xs[16 + srow][sseg4]       = x2;
        *(float4*)&Xs[16 + srow][64 + sseg4]  = x3;
        *(float4*)&Ws[wrow][wseg4]            = w0;
        *(float4*)&Ws[wrow][128 + wseg4]      = w1;
        *(float4*)&Ws[8 + wrow][wseg4]        = w2;
        *(float4*)&Ws[8 + wrow][128 + wseg4]  = w3;
        *(float4*)&Ws[16 + wrow][wseg4]       = w4;
        *(float4*)&Ws[16 + wrow][128 + wseg4] = w5;
        *(float4*)&Ws[24 + wrow][wseg4]       = w6;
        *(float4*)&Ws[24 + wrow][128 + wseg4] = w7;
        __syncthreads();
#pragma unroll
        for (int k = 0; k < 32; ++k) {
            float a[2][4], b[4][4];
            *(float4*)&a[0][0] = *(const float4*)&Xs[k][tx * 4];
            *(float4*)&a[1][0] = *(const float4*)&Xs[k][64 + tx * 4];
#pragma unroll
            for (int q = 0; q < 4; ++q)
                *(float4*)&b[q][0] = *(const float4*)&Ws[k][q * 64 + ty * 4];
#pragma unroll
            for (int p = 0; p < 2; ++p)
#pragma unroll
                for (int i = 0; i < 4; ++i)
#pragma unroll
                    for (int q = 0; q < 4; ++q)
#pragma unroll
                        for (int j = 0; j < 4; ++j)
                            acc[p][i][q][j] = fmaf(a[p][i], b[q][j], acc[p][i][q][j]);
        }
    }
}

// Fused R + Y_D kernel. grid (4,2,64), block 256, 2 blocks/CU (8 waves).
// z<32:  R[b][t][n] = sum_d u[b][d][t] * Bqt[d][n]           (raw)
// z>=32: Pd[b][o][t] = sum_d u[b][d][t] * Dqt[d][o]          (raw, into Y buf)
__global__ __launch_bounds__(256, 2) void gemm_RD(const float* __restrict__ u,
                                                  const float* __restrict__ Bqt,
                                                  const float* __restrict__ Dqt,
                                                  float* __restrict__ R,
                                                  float* __restrict__ Pd) {
    __shared__ float Xs[32][128];
    __shared__ float Ws[32][256];
    const int zz = blockIdx.z;
    const int b  = zz & 31;
    const bool isR = zz < 32;
    const int t0 = blockIdx.x * 128, n0 = blockIdx.y * 256;
    const int tid = threadIdx.x;
    const int tx = tid & 15, ty = tid >> 4;
    const float* ub = u + (size_t)b * (DINX * LSEQ);
    const float* Wm = isR ? Bqt : Dqt;
    float acc[2][4][4][4] = {};
    gemm_pass16(ub, Wm, t0, n0, DINX, acc, Xs, Ws, tid);
    if (isR) {
        float* Rb = R + (size_t)b * (LSEQ * NDIM);
#pragma unroll
        for (int p = 0; p < 2; ++p)
#pragma unroll
            for (int i = 0; i < 4; ++i) {
                float* row = Rb + (size_t)(t0 + p * 64 + tx * 4 + i) * NDIM + n0;
#pragma unroll
                for (int q = 0; q < 4; ++q)
                    *(float4*)(row + q * 64 + ty * 4) =
                        make_float4(acc[p][i][q][0], acc[p][i][q][1],
                                    acc[p][i][q][2], acc[p][i][q][3]);
            }
    } else {
        float* Yb = Pd + (size_t)b * (NDIM * LSEQ);
#pragma unroll
        for (int q = 0; q < 4; ++q)
#pragma unroll
            for (int j = 0; j < 4; ++j) {
                float* row = Yb + (size_t)(n0 + q * 64 + ty * 4 + j) * LSEQ + t0;
                *(float4*)(row + tx * 4)      = make_float4(acc[0][0][q][j], acc[0][1][q][j],
                                                            acc[0][2][q][j], acc[0][3][q][j]);
                *(float4*)(row + 64 + tx * 4) = make_float4(acc[1][0][q][j], acc[1][1][q][j],
                                                            acc[1][2][q][j], acc[1][3][q][j]);
            }
    }
}

// Per-(b, n-chunk) recurrence (bitwise np: mul-then-add, q8). Writes S[b][n][t].
// grid (32, 8), block 64 -> 256 blocks, one chain-wave per CU.
__global__ __launch_bounds__(64) void recur(const float* __restrict__ R,
                                            const float* __restrict__ Aq,
                                            float* __restrict__ S) {
    __shared__ float tile[16][68];
    const int b  = blockIdx.x;
    const int n0 = blockIdx.y * 64;
    const int n  = threadIdx.x;                 // 0..63
    const float a = Aq[n0 + n];
    const float* Rb = R + (size_t)b * (LSEQ * NDIM) + n0;
    float* Sb = S + (size_t)b * (NDIM * LSEQ) + (size_t)n0 * LSEQ;
    float s = 0.0f;
    const int c = (n & 3) * 4;
    const int rbase = n >> 2;                   // 0..15
    for (int t0 = 0; t0 < LSEQ; t0 += 16) {
#pragma unroll
        for (int tt = 0; tt < 16; ++tt) {
            float r = Rb[(size_t)(t0 + tt) * NDIM + n];
            s = q8(__fadd_rn(__fmul_rn(s, a), r));
            tile[tt][n] = s;
        }
        __syncthreads();
#pragma unroll
        for (int p = 0; p < 4; ++p) {
            int row = p * 16 + rbase;
            float4 v = make_float4(tile[c + 0][row], tile[c + 1][row],
                                   tile[c + 2][row], tile[c + 3][row]);
            *(float4*)(Sb + (size_t)row * LSEQ + t0 + c) = v;
        }
        __syncthreads();
    }
}

// Y[b][o][t] = q8( (sum_n S[n][t]*Cqt[n][o]) + Pd[b][o][t] ), Pd staged in Y.
// grid (4,2,32), block 256.
__global__ __launch_bounds__(256, 2) void gemm_YC(const float* __restrict__ S,
                                                  const float* __restrict__ Cqt,
                                                  float* __restrict__ Y) {
    __shared__ float Xs[32][128];
    __shared__ float Ws[32][256];
    const int b  = blockIdx.z;
    const int t0 = blockIdx.x * 128, o0 = blockIdx.y * 256;
    const int tid = threadIdx.x;
    const int tx = tid & 15, ty = tid >> 4;
    const float* Sb = S + (size_t)b * (NDIM * LSEQ);
    float acc[2][4][4][4] = {};
    gemm_pass16(Sb, Cqt, t0, o0, NDIM, acc, Xs, Ws, tid);

    float* Yb = Y + (size_t)b * (NDIM * LSEQ);
#pragma unroll
    for (int q = 0; q < 4; ++q)
#pragma unroll
        for (int j = 0; j < 4; ++j) {
            float* row = Yb + (size_t)(o0 + q * 64 + ty * 4 + j) * LSEQ + t0;
            float4 v0 = *(const float4*)(row + tx * 4);
            float4 v1 = *(const float4*)(row + 64 + tx * 4);
            *(float4*)(row + tx * 4) =
                make_float4(q8(__fadd_rn(acc[0][0][q][j], v0.x)),
                            q8(__fadd_rn(acc[0][1][q][j], v0.y)),
                            q8(__fadd_rn(acc[0][2][q][j], v0.z)),
                            q8(__fadd_rn(acc[0][3][q][j], v0.w)));
            *(float4*)(row + 64 + tx * 4) =
                make_float4(q8(__fadd_rn(acc[1][0][q][j], v1.x)),
                            q8(__fadd_rn(acc[1][1][q][j], v1.y)),
                            q8(__fadd_rn(acc[1][2][q][j], v1.z)),
                            q8(__fadd_rn(acc[1][3][q][j], v1.w)));
        }
}

extern "C" void kernel_launch(void* const* d_in, const int* in_sizes, int n_in,
                              void* d_out, int out_size, void* d_ws, size_t ws_size,
                              hipStream_t stream) {
    const float* u = (const float*)d_in[0];   // (32, 512, 512)
    const float* A = (const float*)d_in[1];   // (512,)
    const float* B = (const float*)d_in[2];   // (512, 512)
    const float* C = (const float*)d_in[3];   // (512, 512)
    const float* D = (const float*)d_in[4];   // (512, 512)

    float* ws  = (float*)d_ws;
    float* Aq  = ws;                    // 512
    float* Bqt = Aq + 512;              // 262144  [d][n]
    float* Cqt = Bqt + 262144;          // 262144  [n][o]
    float* Dqt = Cqt + 262144;          // 262144  [d][o]
    float* R   = Dqt + 262144;          // 8388608 [b][t][n]
    float* S   = R + 8388608;           // 8388608 [b][n][t]
    float* Y   = (float*)d_out;         // 8388608 [b][o][t] (also Pd scratch)

    quantT3A<<<dim3(16, 16, 3), 256, 0, stream>>>(B, C, D, A, Bqt, Cqt, Dqt, Aq);
    gemm_RD<<<dim3(4, 2, 64), 256, 0, stream>>>(u, Bqt, Dqt, R, Y);
    recur<<<dim3(32, 8), 64, 0, stream>>>(R, Aq, S);
    gemm_YC<<<dim3(4, 2, 32), 256, 0, stream>>>(S, Cqt, Y);
}

// Round 6
// 378.989 us; speedup vs baseline: 1.3658x; 1.3157x over previous
//
#include <hip/hip_runtime.h>
#include <hip/hip_bf16.h>

// QuantizedSimpleSSM — round 11: 8x16 tile for RD, spill-proofed. R10's 8x16
// failed by SPILL (VGPR collapsed to 128, WRITE_SIZE +69MB scratch, VALU 41%):
// full k<32 unroll x 6 ds_reads let the scheduler hoist ~190 reads in flight.
// Fix: BK 32->16 (staging 24 regs) + #pragma unroll 2 on k (caps in-flight at
// ~12 float4) -> worst-case live ~215 < 256 cap (launch_bounds(256,2)).
// Only RD changes; YC reverts to R8's proven 8x8 gemm_pass (8x16 YC would be
// 1 block/CU = 1 wave/SIMD). LDS model: RD LDS traffic/CU 34MB -> 25MB, below
// the VALU floor (262k cyc) -> FMA-bound ~160us.
// Numerics contract (absmax 0.0 since R2): every output element is one fp32
// FMA chain in strictly ascending k; recurrence mul-then-add + q8. The 8x16
// epilogue indexing was bitwise-validated in R10 (passed, absmax 0.0).

#define DINX 512
#define LSEQ 512
#define NDIM 512

__device__ __forceinline__ float q8(float x) {
    float xa = fabsf(x);
    float w  = __fadd_rn(xa, 1e-8f);
    int e = (int)((__float_as_uint(w) >> 23) & 0xFFu) - 127;   // floor(log2(w))
    e = e < -7 ? -7 : (e > 7 ? 7 : e);
    float p    = __int_as_float((unsigned)((e + 127) << 23));   // exact 2^e
    float invp = __int_as_float((unsigned)((127 - e) << 23));   // exact 2^-e
    float t  = __fmul_rn(__fsub_rn(__fmul_rn(xa, invp), 1.0f), 8.0f);
    float m  = __fmul_rn(rintf(t), 0.125f);                     // half-to-even
    float r  = __fmul_rn(__fadd_rn(1.0f, m), p);
    return copysignf(r, x);
}

// out[c][r] = q8(in[r][c]) for three 512x512 matrices; block (0,0,0) also
// quants the A vector. grid (16,16,3), block 256.
__global__ __launch_bounds__(256) void quantT3A(const float* __restrict__ B,
                                                const float* __restrict__ C,
                                                const float* __restrict__ D,
                                                const float* __restrict__ A,
                                                float* __restrict__ Bqt,
                                                float* __restrict__ Cqt,
                                                float* __restrict__ Dqt,
                                                float* __restrict__ Aq) {
    __shared__ float tl[32][33];
    if (blockIdx.z == 0 && blockIdx.x == 0 && blockIdx.y == 0) {
        Aq[threadIdx.x]       = q8(A[threadIdx.x]);
        Aq[256 + threadIdx.x] = q8(A[256 + threadIdx.x]);
    }
    const float* in = blockIdx.z == 0 ? B : (blockIdx.z == 1 ? C : D);
    float* out      = blockIdx.z == 0 ? Bqt : (blockIdx.z == 1 ? Cqt : Dqt);
    const int r0 = blockIdx.y * 32, c0 = blockIdx.x * 32;
    const int x = threadIdx.x & 31, y = threadIdx.x >> 5;   // 32 x 8
#pragma unroll
    for (int i = 0; i < 32; i += 8)
        tl[y + i][x] = q8(in[(r0 + y + i) * 512 + c0 + x]);
    __syncthreads();
#pragma unroll
    for (int i = 0; i < 32; i += 8)
        out[(c0 + y + i) * 512 + r0 + x] = tl[x][y + i];
}

// ---------- 8x8 per-thread tile (proven R8 path, used by gemm_YC) ----------
// acc[p][i][q][j] += sum_k X[k][m0 + p*64 + tx*4 + i] * W[k][n0 + q*64 + ty*4 + j]
// k strictly ascending. LDS Xs/Ws [32][128], BK=32 per barrier pair.
__device__ __forceinline__ void gemm_pass(const float* __restrict__ X,
                                          const float* __restrict__ W,
                                          int m0, int n0, int KTOT,
                                          float (&acc)[2][4][2][4],
                                          float (*Xs)[128], float (*Ws)[128],
                                          int tid) {
    const int tx = tid & 15, ty = tid >> 4;
    const int srow = tid >> 4, sseg4 = (tid & 15) * 4;   // 16 rows x 16 chunks
    const float* xp = X + (size_t)srow * 512 + m0 + sseg4;
    const float* wp = W + (size_t)srow * 512 + n0 + sseg4;
    for (int k0 = 0; k0 < KTOT; k0 += 32) {
        float4 x0 = *(const float4*)xp;
        float4 x1 = *(const float4*)(xp + 64);
        float4 x2 = *(const float4*)(xp + 16 * 512);
        float4 x3 = *(const float4*)(xp + 16 * 512 + 64);
        float4 w0 = *(const float4*)wp;
        float4 w1 = *(const float4*)(wp + 64);
        float4 w2 = *(const float4*)(wp + 16 * 512);
        float4 w3 = *(const float4*)(wp + 16 * 512 + 64);
        xp += 32 * 512; wp += 32 * 512;
        __syncthreads();                 // prev-tile reads done before overwrite
        *(float4*)&Xs[srow][sseg4]           = x0;
        *(float4*)&Xs[srow][64 + sseg4]      = x1;
        *(float4*)&Xs[16 + srow][sseg4]      = x2;
        *(float4*)&Xs[16 + srow][64 + sseg4] = x3;
        *(float4*)&Ws[srow][sseg4]           = w0;
        *(float4*)&Ws[srow][64 + sseg4]      = w1;
        *(float4*)&Ws[16 + srow][sseg4]      = w2;
        *(float4*)&Ws[16 + srow][64 + sseg4] = w3;
        __syncthreads();
#pragma unroll
        for (int k = 0; k < 32; ++k) {
            float a[2][4], b[2][4];
            *(float4*)&a[0][0] = *(const float4*)&Xs[k][tx * 4];
            *(float4*)&a[1][0] = *(const float4*)&Xs[k][64 + tx * 4];
            *(float4*)&b[0][0] = *(const float4*)&Ws[k][ty * 4];
            *(float4*)&b[1][0] = *(const float4*)&Ws[k][64 + ty * 4];
#pragma unroll
            for (int p = 0; p < 2; ++p)
#pragma unroll
                for (int i = 0; i < 4; ++i)
#pragma unroll
                    for (int q = 0; q < 2; ++q)
#pragma unroll
                        for (int j = 0; j < 4; ++j)
                            acc[p][i][q][j] = fmaf(a[p][i], b[q][j], acc[p][i][q][j]);
        }
    }
}

// ---------- 8x16 per-thread tile (RD), BK=16, unroll-2 k-loop ----------
// acc[p][i][q][j] += sum_k X[k][m0 + p*64 + tx*4 + i] * W[k][n0 + q*64 + ty*4 + j]
// with q in 0..3 (256-wide n-tile), k strictly ascending.
// LDS: Xs[16][128] (8KB) + Ws[16][256] (16KB), single-buffered.
__device__ __forceinline__ void gemm_pass16(const float* __restrict__ X,
                                            const float* __restrict__ W,
                                            int m0, int n0, int KTOT,
                                            float (&acc)[2][4][4][4],
                                            float (*Xs)[128], float (*Ws)[256],
                                            int tid) {
    const int tx = tid & 15, ty = tid >> 4;              // 16 x 16 thread grid
    const int srow = tid >> 4, sseg4 = (tid & 15) * 4;   // X staging: 16r x 16c
    const int wrow = tid >> 6, wseg4 = (tid & 63) * 4;   // W staging: 4r x 64c
    const float* xp = X + (size_t)srow * 512 + m0 + sseg4;
    const float* wp = W + (size_t)wrow * 512 + n0 + wseg4;
    for (int k0 = 0; k0 < KTOT; k0 += 16) {
        float4 x0 = *(const float4*)xp;
        float4 x1 = *(const float4*)(xp + 64);
        float4 w0 = *(const float4*)wp;
        float4 w1 = *(const float4*)(wp + 4 * 512);
        float4 w2 = *(const float4*)(wp + 8 * 512);
        float4 w3 = *(const float4*)(wp + 12 * 512);
        xp += 16 * 512; wp += 16 * 512;
        __syncthreads();                 // prev-tile reads done before overwrite
        *(float4*)&Xs[srow][sseg4]       = x0;
        *(float4*)&Xs[srow][64 + sseg4]  = x1;
        *(float4*)&Ws[wrow][wseg4]       = w0;
        *(float4*)&Ws[4 + wrow][wseg4]   = w1;
        *(float4*)&Ws[8 + wrow][wseg4]   = w2;
        *(float4*)&Ws[12 + wrow][wseg4]  = w3;
        __syncthreads();
#pragma unroll 2
        for (int k = 0; k < 16; ++k) {
            float a[2][4], b[4][4];
            *(float4*)&a[0][0] = *(const float4*)&Xs[k][tx * 4];
            *(float4*)&a[1][0] = *(const float4*)&Xs[k][64 + tx * 4];
#pragma unroll
            for (int q = 0; q < 4; ++q)
                *(float4*)&b[q][0] = *(const float4*)&Ws[k][q * 64 + ty * 4];
#pragma unroll
            for (int p = 0; p < 2; ++p)
#pragma unroll
                for (int i = 0; i < 4; ++i)
#pragma unroll
                    for (int q = 0; q < 4; ++q)
#pragma unroll
                        for (int j = 0; j < 4; ++j)
                            acc[p][i][q][j] = fmaf(a[p][i], b[q][j], acc[p][i][q][j]);
        }
    }
}

// Fused R + Y_D kernel, 8x16 tile (128t x 256n per block). grid (4,2,64),
// block 256, 2 blocks/CU (8 waves).
// z<32:  R[b][t][n] = sum_d u[b][d][t] * Bqt[d][n]           (raw)
// z>=32: Pd[b][o][t] = sum_d u[b][d][t] * Dqt[d][o]          (raw, into Y buf)
__global__ __launch_bounds__(256, 2) void gemm_RD(const float* __restrict__ u,
                                                  const float* __restrict__ Bqt,
                                                  const float* __restrict__ Dqt,
                                                  float* __restrict__ R,
                                                  float* __restrict__ Pd) {
    __shared__ float Xs[16][128];
    __shared__ float Ws[16][256];
    const int zz = blockIdx.z;
    const int b  = zz & 31;
    const bool isR = zz < 32;
    const int t0 = blockIdx.x * 128, n0 = blockIdx.y * 256;
    const int tid = threadIdx.x;
    const int tx = tid & 15, ty = tid >> 4;
    const float* ub = u + (size_t)b * (DINX * LSEQ);
    const float* Wm = isR ? Bqt : Dqt;
    float acc[2][4][4][4] = {};
    gemm_pass16(ub, Wm, t0, n0, DINX, acc, Xs, Ws, tid);
    if (isR) {
        float* Rb = R + (size_t)b * (LSEQ * NDIM);
#pragma unroll
        for (int p = 0; p < 2; ++p)
#pragma unroll
            for (int i = 0; i < 4; ++i) {
                float* row = Rb + (size_t)(t0 + p * 64 + tx * 4 + i) * NDIM + n0;
#pragma unroll
                for (int q = 0; q < 4; ++q)
                    *(float4*)(row + q * 64 + ty * 4) =
                        make_float4(acc[p][i][q][0], acc[p][i][q][1],
                                    acc[p][i][q][2], acc[p][i][q][3]);
            }
    } else {
        float* Yb = Pd + (size_t)b * (NDIM * LSEQ);
#pragma unroll
        for (int q = 0; q < 4; ++q)
#pragma unroll
            for (int j = 0; j < 4; ++j) {
                float* row = Yb + (size_t)(n0 + q * 64 + ty * 4 + j) * LSEQ + t0;
                *(float4*)(row + tx * 4)      = make_float4(acc[0][0][q][j], acc[0][1][q][j],
                                                            acc[0][2][q][j], acc[0][3][q][j]);
                *(float4*)(row + 64 + tx * 4) = make_float4(acc[1][0][q][j], acc[1][1][q][j],
                                                            acc[1][2][q][j], acc[1][3][q][j]);
            }
    }
}

// Per-(b, n-chunk) recurrence (bitwise np: mul-then-add, q8). Writes S[b][n][t].
// grid (32, 8), block 64 -> 256 blocks, one chain-wave per CU.
__global__ __launch_bounds__(64) void recur(const float* __restrict__ R,
                                            const float* __restrict__ Aq,
                                            float* __restrict__ S) {
    __shared__ float tile[16][68];
    const int b  = blockIdx.x;
    const int n0 = blockIdx.y * 64;
    const int n  = threadIdx.x;                 // 0..63
    const float a = Aq[n0 + n];
    const float* Rb = R + (size_t)b * (LSEQ * NDIM) + n0;
    float* Sb = S + (size_t)b * (NDIM * LSEQ) + (size_t)n0 * LSEQ;
    float s = 0.0f;
    const int c = (n & 3) * 4;
    const int rbase = n >> 2;                   // 0..15
    for (int t0 = 0; t0 < LSEQ; t0 += 16) {
#pragma unroll
        for (int tt = 0; tt < 16; ++tt) {
            float r = Rb[(size_t)(t0 + tt) * NDIM + n];
            s = q8(__fadd_rn(__fmul_rn(s, a), r));
            tile[tt][n] = s;
        }
        __syncthreads();
#pragma unroll
        for (int p = 0; p < 4; ++p) {
            int row = p * 16 + rbase;
            float4 v = make_float4(tile[c + 0][row], tile[c + 1][row],
                                   tile[c + 2][row], tile[c + 3][row]);
            *(float4*)(Sb + (size_t)row * LSEQ + t0 + c) = v;
        }
        __syncthreads();
    }
}

// Y[b][o][t] = q8( (sum_n S[n][t]*Cqt[n][o]) + Pd[b][o][t] ), Pd staged in Y.
// grid (4,4,32), block 256 — proven R8 8x8 path.
__global__ __launch_bounds__(256) void gemm_YC(const float* __restrict__ S,
                                               const float* __restrict__ Cqt,
                                               float* __restrict__ Y) {
    __shared__ float Xs[32][128];
    __shared__ float Ws[32][128];
    const int b  = blockIdx.z;
    const int t0 = blockIdx.x * 128, o0 = blockIdx.y * 128;
    const int tid = threadIdx.x;
    const int tx = tid & 15, ty = tid >> 4;
    const float* Sb = S + (size_t)b * (NDIM * LSEQ);
    float acc[2][4][2][4] = {};
    gemm_pass(Sb, Cqt, t0, o0, NDIM, acc, Xs, Ws, tid);

    float* Yb = Y + (size_t)b * (NDIM * LSEQ);
#pragma unroll
    for (int q = 0; q < 2; ++q)
#pragma unroll
        for (int j = 0; j < 4; ++j) {
            float* row = Yb + (size_t)(o0 + q * 64 + ty * 4 + j) * LSEQ + t0;
            float4 v0 = *(const float4*)(row + tx * 4);
            float4 v1 = *(const float4*)(row + 64 + tx * 4);
            *(float4*)(row + tx * 4) =
                make_float4(q8(__fadd_rn(acc[0][0][q][j], v0.x)),
                            q8(__fadd_rn(acc[0][1][q][j], v0.y)),
                            q8(__fadd_rn(acc[0][2][q][j], v0.z)),
                            q8(__fadd_rn(acc[0][3][q][j], v0.w)));
            *(float4*)(row + 64 + tx * 4) =
                make_float4(q8(__fadd_rn(acc[1][0][q][j], v1.x)),
                            q8(__fadd_rn(acc[1][1][q][j], v1.y)),
                            q8(__fadd_rn(acc[1][2][q][j], v1.z)),
                            q8(__fadd_rn(acc[1][3][q][j], v1.w)));
        }
}

extern "C" void kernel_launch(void* const* d_in, const int* in_sizes, int n_in,
                              void* d_out, int out_size, void* d_ws, size_t ws_size,
                              hipStream_t stream) {
    const float* u = (const float*)d_in[0];   // (32, 512, 512)
    const float* A = (const float*)d_in[1];   // (512,)
    const float* B = (const float*)d_in[2];   // (512, 512)
    const float* C = (const float*)d_in[3];   // (512, 512)
    const float* D = (const float*)d_in[4];   // (512, 512)

    float* ws  = (float*)d_ws;
    float* Aq  = ws;                    // 512
    float* Bqt = Aq + 512;              // 262144  [d][n]
    float* Cqt = Bqt + 262144;          // 262144  [n][o]
    float* Dqt = Cqt + 262144;          // 262144  [d][o]
    float* R   = Dqt + 262144;          // 8388608 [b][t][n]
    float* S   = R + 8388608;           // 8388608 [b][n][t]
    float* Y   = (float*)d_out;         // 8388608 [b][o][t] (also Pd scratch)

    quantT3A<<<dim3(16, 16, 3), 256, 0, stream>>>(B, C, D, A, Bqt, Cqt, Dqt, Aq);
    gemm_RD<<<dim3(4, 2, 64), 256, 0, stream>>>(u, Bqt, Dqt, R, Y);
    recur<<<dim3(32, 8), 64, 0, stream>>>(R, Aq, S);
    gemm_YC<<<dim3(4, 4, 32), 256, 0, stream>>>(S, Cqt, Y);
}

// Round 7
// 369.909 us; speedup vs baseline: 1.3993x; 1.0245x over previous
//
#include <hip/hip_runtime.h>

// QuantizedSimpleSSM — round 12: pipeline de-serialization. R6-R11 showed the
// GEMM inner loop plateaus with VALU~65%/LDS~60% (both pipes part-busy, every
// intra-loop lever <±5%). Remaining serialized time: recur (~45us at 1 active
// wave/CU, 3 SIMDs idle) and quantC/D (~8us). recur depends only on R; the
// D-GEMM depends only on u,Dqt -> fuse them as disjoint block ranges of one
// kernel (recur blocks first -> 1/CU, D blocks fill the CU around them).
// Likewise quantC/D blocks ride in the R-GEMM launch. 8x8 gemm_pass (R8
// bit-exact) everywhere; R11's 8x16 dropped (was only -5%, regresses at the
// fusion's occupancy). All chains/epilogues copied bit-exact -> absmax 0.0.
// Numerics contract (absmax 0.0 since R2): every output element is one fp32
// FMA chain in strictly ascending k; recurrence mul-then-add + q8.

#define DINX 512
#define LSEQ 512
#define NDIM 512

__device__ __forceinline__ float q8(float x) {
    float xa = fabsf(x);
    float w  = __fadd_rn(xa, 1e-8f);
    int e = (int)((__float_as_uint(w) >> 23) & 0xFFu) - 127;   // floor(log2(w))
    e = e < -7 ? -7 : (e > 7 ? 7 : e);
    float p    = __int_as_float((unsigned)((e + 127) << 23));   // exact 2^e
    float invp = __int_as_float((unsigned)((127 - e) << 23));   // exact 2^-e
    float t  = __fmul_rn(__fsub_rn(__fmul_rn(xa, invp), 1.0f), 8.0f);
    float m  = __fmul_rn(rintf(t), 0.125f);                     // half-to-even
    float r  = __fmul_rn(__fadd_rn(1.0f, m), p);
    return copysignf(r, x);
}

// Bqt[c][r] = q8(B[r][c]); block (0,0) also quants A. grid (16,16), block 256.
__global__ __launch_bounds__(256) void quantBA(const float* __restrict__ B,
                                               const float* __restrict__ A,
                                               float* __restrict__ Bqt,
                                               float* __restrict__ Aq) {
    __shared__ float tl[32][33];
    if (blockIdx.x == 0 && blockIdx.y == 0) {
        Aq[threadIdx.x]       = q8(A[threadIdx.x]);
        Aq[256 + threadIdx.x] = q8(A[256 + threadIdx.x]);
    }
    const int r0 = blockIdx.y * 32, c0 = blockIdx.x * 32;
    const int x = threadIdx.x & 31, y = threadIdx.x >> 5;   // 32 x 8
#pragma unroll
    for (int i = 0; i < 32; i += 8)
        tl[y + i][x] = q8(B[(r0 + y + i) * 512 + c0 + x]);
    __syncthreads();
#pragma unroll
    for (int i = 0; i < 32; i += 8)
        Bqt[(c0 + y + i) * 512 + r0 + x] = tl[x][y + i];
}

// 8x8 per-thread tile (R8 bit-exact path).
// acc[p][i][q][j] += sum_k X[k][m0 + p*64 + tx*4 + i] * W[k][n0 + q*64 + ty*4 + j]
// k strictly ascending. LDS Xs/Ws [32][128], BK=32 per barrier pair.
__device__ __forceinline__ void gemm_pass(const float* __restrict__ X,
                                          const float* __restrict__ W,
                                          int m0, int n0, int KTOT,
                                          float (&acc)[2][4][2][4],
                                          float (*Xs)[128], float (*Ws)[128],
                                          int tid) {
    const int tx = tid & 15, ty = tid >> 4;
    const int srow = tid >> 4, sseg4 = (tid & 15) * 4;   // 16 rows x 16 chunks
    const float* xp = X + (size_t)srow * 512 + m0 + sseg4;
    const float* wp = W + (size_t)srow * 512 + n0 + sseg4;
    for (int k0 = 0; k0 < KTOT; k0 += 32) {
        float4 x0 = *(const float4*)xp;
        float4 x1 = *(const float4*)(xp + 64);
        float4 x2 = *(const float4*)(xp + 16 * 512);
        float4 x3 = *(const float4*)(xp + 16 * 512 + 64);
        float4 w0 = *(const float4*)wp;
        float4 w1 = *(const float4*)(wp + 64);
        float4 w2 = *(const float4*)(wp + 16 * 512);
        float4 w3 = *(const float4*)(wp + 16 * 512 + 64);
        xp += 32 * 512; wp += 32 * 512;
        __syncthreads();                 // prev-tile reads done before overwrite
        *(float4*)&Xs[srow][sseg4]           = x0;
        *(float4*)&Xs[srow][64 + sseg4]      = x1;
        *(float4*)&Xs[16 + srow][sseg4]      = x2;
        *(float4*)&Xs[16 + srow][64 + sseg4] = x3;
        *(float4*)&Ws[srow][sseg4]           = w0;
        *(float4*)&Ws[srow][64 + sseg4]      = w1;
        *(float4*)&Ws[16 + srow][sseg4]      = w2;
        *(float4*)&Ws[16 + srow][64 + sseg4] = w3;
        __syncthreads();
#pragma unroll
        for (int k = 0; k < 32; ++k) {
            float a[2][4], b[2][4];
            *(float4*)&a[0][0] = *(const float4*)&Xs[k][tx * 4];
            *(float4*)&a[1][0] = *(const float4*)&Xs[k][64 + tx * 4];
            *(float4*)&b[0][0] = *(const float4*)&Ws[k][ty * 4];
            *(float4*)&b[1][0] = *(const float4*)&Ws[k][64 + ty * 4];
#pragma unroll
            for (int p = 0; p < 2; ++p)
#pragma unroll
                for (int i = 0; i < 4; ++i)
#pragma unroll
                    for (int q = 0; q < 2; ++q)
#pragma unroll
                        for (int j = 0; j < 4; ++j)
                            acc[p][i][q][j] = fmaf(a[p][i], b[q][j], acc[p][i][q][j]);
        }
    }
}

// Fused: blocks 0..511 = R-GEMM (R[b][t][n] = sum_d u[b][d][t]*Bqt[d][n]);
// blocks 512..1023 = C/D quant-transpose (independent, needed only later).
// grid 1024, block 256, 4 blocks/CU.
__global__ __launch_bounds__(256, 4) void fused_RqCD(const float* __restrict__ u,
                                                     const float* __restrict__ Bqt,
                                                     const float* __restrict__ C,
                                                     const float* __restrict__ D,
                                                     float* __restrict__ R,
                                                     float* __restrict__ Cqt,
                                                     float* __restrict__ Dqt) {
    __shared__ float ldsbuf[2 * 32 * 128];   // 32 KB
    const int zz = blockIdx.x;
    const int tid = threadIdx.x;
    if (zz < 512) {
        float (*Xs)[128] = (float(*)[128])ldsbuf;
        float (*Ws)[128] = (float(*)[128])(ldsbuf + 32 * 128);
        const int b = zz & 31, t0 = ((zz >> 5) & 3) * 128, n0 = (zz >> 7) * 128;
        const int tx = tid & 15, ty = tid >> 4;
        const float* ub = u + (size_t)b * (DINX * LSEQ);
        float acc[2][4][2][4] = {};
        gemm_pass(ub, Bqt, t0, n0, DINX, acc, Xs, Ws, tid);
        float* Rb = R + (size_t)b * (LSEQ * NDIM);
#pragma unroll
        for (int p = 0; p < 2; ++p)
#pragma unroll
            for (int i = 0; i < 4; ++i) {
                float* row = Rb + (size_t)(t0 + p * 64 + tx * 4 + i) * NDIM + n0;
                *(float4*)(row + ty * 4)      = make_float4(acc[p][i][0][0], acc[p][i][0][1],
                                                            acc[p][i][0][2], acc[p][i][0][3]);
                *(float4*)(row + 64 + ty * 4) = make_float4(acc[p][i][1][0], acc[p][i][1][1],
                                                            acc[p][i][1][2], acc[p][i][1][3]);
            }
    } else {
        float (*tl)[33] = (float(*)[33])ldsbuf;
        const int d = zz - 512;
        const float* in = (d >> 8) ? D : C;
        float* out      = (d >> 8) ? Dqt : Cqt;
        const int c0 = (d & 15) * 32, r0 = ((d >> 4) & 15) * 32;
        const int x = tid & 31, y = tid >> 5;   // 32 x 8
#pragma unroll
        for (int i = 0; i < 32; i += 8)
            tl[y + i][x] = q8(in[(r0 + y + i) * 512 + c0 + x]);
        __syncthreads();
#pragma unroll
        for (int i = 0; i < 32; i += 8)
            out[(c0 + y + i) * 512 + r0 + x] = tl[x][y + i];
    }
}

// Fused: blocks 0..255 = recurrence (dispatch first -> ~1/CU, hidden under D);
// blocks 256..767 = D-GEMM (Pd[b][o][t] = sum_d u[b][d][t]*Dqt[d][o], raw into
// Y scratch). grid 768, block 256, 3 blocks/CU (12 waves: 8 D + 4 recur).
__global__ __launch_bounds__(256, 3) void fused_Drec(const float* __restrict__ u,
                                                     const float* __restrict__ Dqt,
                                                     const float* __restrict__ R,
                                                     const float* __restrict__ Aq,
                                                     float* __restrict__ Pd,
                                                     float* __restrict__ S) {
    __shared__ float ldsbuf[2 * 32 * 128];   // 32 KB
    const int zz = blockIdx.x;
    const int tid = threadIdx.x;
    if (zz >= 256) {
        // ---- D-GEMM (R8 bit-exact else-branch) ----
        float (*Xs)[128] = (float(*)[128])ldsbuf;
        float (*Ws)[128] = (float(*)[128])(ldsbuf + 32 * 128);
        const int d = zz - 256;
        const int b = d & 31, t0 = ((d >> 5) & 3) * 128, o0 = (d >> 7) * 128;
        const int tx = tid & 15, ty = tid >> 4;
        const float* ub = u + (size_t)b * (DINX * LSEQ);
        float acc[2][4][2][4] = {};
        gemm_pass(ub, Dqt, t0, o0, DINX, acc, Xs, Ws, tid);
        float* Yb = Pd + (size_t)b * (NDIM * LSEQ);
#pragma unroll
        for (int q = 0; q < 2; ++q)
#pragma unroll
            for (int j = 0; j < 4; ++j) {
                float* row = Yb + (size_t)(o0 + q * 64 + ty * 4 + j) * LSEQ + t0;
                *(float4*)(row + tx * 4)      = make_float4(acc[0][0][q][j], acc[0][1][q][j],
                                                            acc[0][2][q][j], acc[0][3][q][j]);
                *(float4*)(row + 64 + tx * 4) = make_float4(acc[1][0][q][j], acc[1][1][q][j],
                                                            acc[1][2][q][j], acc[1][3][q][j]);
            }
    } else {
        // ---- recurrence (bit-exact chain; tid<64 active, all barrier) ----
        float (*tile)[68] = (float(*)[68])ldsbuf;
        const int b  = zz >> 3;
        const int n0 = (zz & 7) * 64;
        const int n  = tid & 63;
        const bool act = tid < 64;
        float a = 0.0f, s = 0.0f;
        const float* Rb = R + (size_t)b * (LSEQ * NDIM) + n0;
        float* Sb = S + (size_t)b * (NDIM * LSEQ) + (size_t)n0 * LSEQ;
        if (act) a = Aq[n0 + n];
        const int c = (n & 3) * 4;
        const int rbase = n >> 2;                   // 0..15
        for (int t0 = 0; t0 < LSEQ; t0 += 16) {
            if (act) {
#pragma unroll
                for (int tt = 0; tt < 16; ++tt) {
                    float r = Rb[(size_t)(t0 + tt) * NDIM + n];
                    s = q8(__fadd_rn(__fmul_rn(s, a), r));
                    tile[tt][n] = s;
                }
            }
            __syncthreads();
            if (act) {
#pragma unroll
                for (int p = 0; p < 4; ++p) {
                    int row = p * 16 + rbase;
                    float4 v = make_float4(tile[c + 0][row], tile[c + 1][row],
                                           tile[c + 2][row], tile[c + 3][row]);
                    *(float4*)(Sb + (size_t)row * LSEQ + t0 + c) = v;
                }
            }
            __syncthreads();
        }
    }
}

// Y[b][o][t] = q8( (sum_n S[n][t]*Cqt[n][o]) + Pd[b][o][t] ), Pd staged in Y.
// grid (4,4,32), block 256 — R8/R11 bit-exact path.
__global__ __launch_bounds__(256) void gemm_YC(const float* __restrict__ S,
                                               const float* __restrict__ Cqt,
                                               float* __restrict__ Y) {
    __shared__ float Xs[32][128];
    __shared__ float Ws[32][128];
    const int b  = blockIdx.z;
    const int t0 = blockIdx.x * 128, o0 = blockIdx.y * 128;
    const int tid = threadIdx.x;
    const int tx = tid & 15, ty = tid >> 4;
    const float* Sb = S + (size_t)b * (NDIM * LSEQ);
    float acc[2][4][2][4] = {};
    gemm_pass(Sb, Cqt, t0, o0, NDIM, acc, Xs, Ws, tid);

    float* Yb = Y + (size_t)b * (NDIM * LSEQ);
#pragma unroll
    for (int q = 0; q < 2; ++q)
#pragma unroll
        for (int j = 0; j < 4; ++j) {
            float* row = Yb + (size_t)(o0 + q * 64 + ty * 4 + j) * LSEQ + t0;
            float4 v0 = *(const float4*)(row + tx * 4);
            float4 v1 = *(const float4*)(row + 64 + tx * 4);
            *(float4*)(row + tx * 4) =
                make_float4(q8(__fadd_rn(acc[0][0][q][j], v0.x)),
                            q8(__fadd_rn(acc[0][1][q][j], v0.y)),
                            q8(__fadd_rn(acc[0][2][q][j], v0.z)),
                            q8(__fadd_rn(acc[0][3][q][j], v0.w)));
            *(float4*)(row + 64 + tx * 4) =
                make_float4(q8(__fadd_rn(acc[1][0][q][j], v1.x)),
                            q8(__fadd_rn(acc[1][1][q][j], v1.y)),
                            q8(__fadd_rn(acc[1][2][q][j], v1.z)),
                            q8(__fadd_rn(acc[1][3][q][j], v1.w)));
        }
}

extern "C" void kernel_launch(void* const* d_in, const int* in_sizes, int n_in,
                              void* d_out, int out_size, void* d_ws, size_t ws_size,
                              hipStream_t stream) {
    const float* u = (const float*)d_in[0];   // (32, 512, 512)
    const float* A = (const float*)d_in[1];   // (512,)
    const float* B = (const float*)d_in[2];   // (512, 512)
    const float* C = (const float*)d_in[3];   // (512, 512)
    const float* D = (const float*)d_in[4];   // (512, 512)

    float* ws  = (float*)d_ws;
    float* Aq  = ws;                    // 512
    float* Bqt = Aq + 512;              // 262144  [d][n]
    float* Cqt = Bqt + 262144;          // 262144  [n][o]
    float* Dqt = Cqt + 262144;          // 262144  [d][o]
    float* R   = Dqt + 262144;          // 8388608 [b][t][n]
    float* S   = R + 8388608;           // 8388608 [b][n][t]
    float* Y   = (float*)d_out;         // 8388608 [b][o][t] (also Pd scratch)

    quantBA<<<dim3(16, 16), 256, 0, stream>>>(B, A, Bqt, Aq);
    fused_RqCD<<<1024, 256, 0, stream>>>(u, Bqt, C, D, R, Cqt, Dqt);
    fused_Drec<<<768, 256, 0, stream>>>(u, Dqt, R, Aq, Y, S);
    gemm_YC<<<dim3(4, 4, 32), 256, 0, stream>>>(S, Cqt, Y);
}